// Round 1
// baseline (1041.984 us; speedup 1.0000x reference)
//
#include <hip/hip_runtime.h>
#include <math.h>

// BiLSTM-CRF fp32 baseline.
// ws layout (floats): x[16384*256] | G[16384*2048] | hs_f[32*512*256] |
//                     hs_b[32*512*256] | c_f[512*256] | c_b[512*256] | feats[16384*11]
// total ~178 MiB. Output: d_out[0:32]=score(f32), d_out[32:32+16384]=path (float-encoded ints).

namespace {

constexpr int E_ = 256;    // embed dim
constexpr int H_ = 256;    // hidden per dir
constexpr int T_ = 11;     // tags

// ---------------- K1: embedding gather ----------------
__global__ __launch_bounds__(256) void k_gather(const int* __restrict__ sent,
                                                const float* __restrict__ embed,
                                                float* __restrict__ x) {
  int i = blockIdx.x * 256 + threadIdx.x;   // float4 id over 16384*64
  int row = i >> 6;
  int e = (i & 63) << 2;
  int tok = sent[row];
  *(float4*)(x + (size_t)row * E_ + e) =
      *(const float4*)(embed + (size_t)tok * E_ + e);
}

// ---------------- K2: input GEMM  G[row][n] = sum_k x[row][k]*W[n][k] + bias ----------------
// n in [0,1024): fwd gates (i,f,g,o each 256); n in [1024,2048): bwd gates.
__global__ __launch_bounds__(256) void k_input_gemm(
    const float* __restrict__ x,
    const float* __restrict__ w_ih_f, const float* __restrict__ w_ih_b,
    const float* __restrict__ b_ih_f, const float* __restrict__ b_hh_f,
    const float* __restrict__ b_ih_b, const float* __restrict__ b_hh_b,
    float* __restrict__ G) {
  __shared__ __align__(16) float As[16][128];
  __shared__ __align__(16) float Bs[16][128];
  const int tid = threadIdx.x;
  const int col0 = blockIdx.x * 128;        // 0..1920
  const int row0 = blockIdx.y * 128;
  const int dir = col0 >> 10;               // BN=128 divides 1024: no straddle
  const float* W = dir ? w_ih_b : w_ih_f;
  const int nc0 = col0 & 1023;
  const int tx = tid & 15, ty = tid >> 4;
  float acc[8][8];
#pragma unroll
  for (int i = 0; i < 8; ++i)
#pragma unroll
    for (int j = 0; j < 8; ++j) acc[i][j] = 0.f;

  for (int k0 = 0; k0 < E_; k0 += 16) {
#pragma unroll
    for (int i = 0; i < 2; ++i) {
      int L = tid * 2 + i;
      int r = L >> 2, k = (L & 3) << 2;
      float4 v = *(const float4*)(x + (size_t)(row0 + r) * E_ + k0 + k);
      As[k + 0][r] = v.x; As[k + 1][r] = v.y; As[k + 2][r] = v.z; As[k + 3][r] = v.w;
      float4 w = *(const float4*)(W + (size_t)(nc0 + r) * E_ + k0 + k);
      Bs[k + 0][r] = w.x; Bs[k + 1][r] = w.y; Bs[k + 2][r] = w.z; Bs[k + 3][r] = w.w;
    }
    __syncthreads();
#pragma unroll
    for (int kk = 0; kk < 16; ++kk) {
      float a[8], b[8];
      *(float4*)&a[0] = *(const float4*)&As[kk][ty * 8];
      *(float4*)&a[4] = *(const float4*)&As[kk][ty * 8 + 4];
      *(float4*)&b[0] = *(const float4*)&Bs[kk][tx * 8];
      *(float4*)&b[4] = *(const float4*)&Bs[kk][tx * 8 + 4];
#pragma unroll
      for (int i = 0; i < 8; ++i)
#pragma unroll
        for (int j = 0; j < 8; ++j) acc[i][j] = fmaf(a[i], b[j], acc[i][j]);
    }
    __syncthreads();
  }
  const float* bi = dir ? b_ih_b : b_ih_f;
  const float* bh = dir ? b_hh_b : b_hh_f;
  float bias[8];
#pragma unroll
  for (int j = 0; j < 8; ++j) {
    int n = nc0 + tx * 8 + j;
    bias[j] = bi[n] + bh[n];
  }
#pragma unroll
  for (int i = 0; i < 8; ++i) {
    size_t r = row0 + ty * 8 + i;
    float o0[4], o1[4];
#pragma unroll
    for (int j = 0; j < 4; ++j) { o0[j] = acc[i][j] + bias[j]; o1[j] = acc[i][j + 4] + bias[j + 4]; }
    *(float4*)(G + r * 2048 + col0 + tx * 8) = *(float4*)o0;
    *(float4*)(G + r * 2048 + col0 + tx * 8 + 4) = *(float4*)o1;
  }
}

// ---------------- K3: one LSTM recurrence step (both directions) ----------------
// Block computes h/c tile: 32 rows (s) x 32 cols (j). GEMM gates = h_prev @ w_hh.T
// for 4 gate quadrants (i,f,g,o) of those 32 cols -> Cs[32][128], then pointwise.
__global__ __launch_bounds__(256) void k_lstm_step(
    const float* __restrict__ G,
    const float* __restrict__ w_hh_f, const float* __restrict__ w_hh_b,
    const float* __restrict__ h0, const float* __restrict__ c0,
    float* __restrict__ hs_f, float* __restrict__ hs_b,
    float* __restrict__ c_f, float* __restrict__ c_b, int t) {
  __shared__ __align__(16) float As[32][32];
  __shared__ __align__(16) float Bs[32][128];
  __shared__ __align__(16) float Cs[32][128];
  const int tid = threadIdx.x;
  const int cb = blockIdx.x;       // 0..7  (j block)
  const int rb = blockIdx.y;       // 0..15 (s block)
  const int d = blockIdx.z;        // 0 fwd, 1 bwd
  const int r0 = rb * 32;
  const int j0 = cb * 32;
  const float* whh = d ? w_hh_b : w_hh_f;
  const float* hprev = (t == 0) ? (h0 + (size_t)d * 512 * H_)
                     : (d == 0 ? hs_f + (size_t)(t - 1) * 512 * H_
                               : hs_b + (size_t)(32 - t) * 512 * H_);
  const int tt = (d == 0) ? t : 31 - t;     // which time slice of G / x
  float* hout = (d == 0) ? hs_f + (size_t)t * 512 * H_
                         : hs_b + (size_t)(31 - t) * 512 * H_;
  float* cbuf = d ? c_b : c_f;
  const float* cprev = (t == 0) ? (c0 + (size_t)d * 512 * H_) : cbuf;

  const int tx = tid & 31, ty = tid >> 5;   // tx: 4-col group, ty: 4-row group
  float acc[4][4];
#pragma unroll
  for (int i = 0; i < 4; ++i)
#pragma unroll
    for (int j = 0; j < 4; ++j) acc[i][j] = 0.f;

  for (int k0 = 0; k0 < H_; k0 += 32) {
    {
      int r = tid >> 3, k = (tid & 7) << 2;
      float4 v = *(const float4*)(hprev + (size_t)(r0 + r) * H_ + k0 + k);
      As[k + 0][r] = v.x; As[k + 1][r] = v.y; As[k + 2][r] = v.z; As[k + 3][r] = v.w;
    }
#pragma unroll
    for (int i = 0; i < 4; ++i) {
      int L = tid + 256 * i;
      int col = L >> 3, k = (L & 7) << 2;   // col 0..127 = q*32+jj
      int q = col >> 5, jj = col & 31;
      float4 v = *(const float4*)(whh + (size_t)(q * 256 + j0 + jj) * H_ + k0 + k);
      Bs[k + 0][col] = v.x; Bs[k + 1][col] = v.y; Bs[k + 2][col] = v.z; Bs[k + 3][col] = v.w;
    }
    __syncthreads();
#pragma unroll
    for (int kk = 0; kk < 32; ++kk) {
      float4 av = *(const float4*)&As[kk][ty * 4];
      float4 bv = *(const float4*)&Bs[kk][tx * 4];
      float a[4] = {av.x, av.y, av.z, av.w};
      float b[4] = {bv.x, bv.y, bv.z, bv.w};
#pragma unroll
      for (int i = 0; i < 4; ++i)
#pragma unroll
        for (int j = 0; j < 4; ++j) acc[i][j] = fmaf(a[i], b[j], acc[i][j]);
    }
    __syncthreads();
  }
#pragma unroll
  for (int i = 0; i < 4; ++i)
    *(float4*)&Cs[ty * 4 + i][tx * 4] =
        make_float4(acc[i][0], acc[i][1], acc[i][2], acc[i][3]);
  __syncthreads();

  // pointwise: 1024 cells, 4 per thread
#pragma unroll
  for (int u = 0; u < 4; ++u) {
    int idx = tid + 256 * u;
    int sl = idx >> 5, jj = idx & 31;
    int s = r0 + sl, j = j0 + jj;
    const float* g = G + ((size_t)tt * 512 + s) * 2048 + (size_t)d * 1024;
    float gi = Cs[sl][jj]       + g[0 * 256 + j0 + jj];
    float gf = Cs[sl][32 + jj]  + g[1 * 256 + j0 + jj];
    float gg = Cs[sl][64 + jj]  + g[2 * 256 + j0 + jj];
    float go = Cs[sl][96 + jj]  + g[3 * 256 + j0 + jj];
    float si = 1.f / (1.f + expf(-gi));
    float sf = 1.f / (1.f + expf(-gf));
    float tg = tanhf(gg);
    float so = 1.f / (1.f + expf(-go));
    float cp = cprev[(size_t)s * H_ + j];
    float cn = sf * cp + si * tg;
    float hn = so * tanhf(cn);
    cbuf[(size_t)s * H_ + j] = cn;
    hout[(size_t)s * H_ + j] = hn;
  }
}

// ---------------- K4: feats = [hs_f|hs_b] @ w_out.T + b_out ----------------
__global__ __launch_bounds__(256) void k_out_gemm(
    const float* __restrict__ hs_f, const float* __restrict__ hs_b,
    const float* __restrict__ w_out, const float* __restrict__ b_out,
    float* __restrict__ feats) {
  __shared__ __align__(16) float wl[T_ * 512];
  for (int i = threadIdx.x; i < T_ * 512; i += 256) wl[i] = w_out[i];
  __syncthreads();
  int wave = threadIdx.x >> 6, lane = threadIdx.x & 63;
  size_t row = (size_t)blockIdx.x * 4 + wave;   // 0..16383
  float4 hf = *(const float4*)(hs_f + row * H_ + lane * 4);
  float4 hb = *(const float4*)(hs_b + row * H_ + lane * 4);
#pragma unroll
  for (int tag = 0; tag < T_; ++tag) {
    float4 wf = *(const float4*)&wl[tag * 512 + lane * 4];
    float4 wb = *(const float4*)&wl[tag * 512 + 256 + lane * 4];
    float p = hf.x * wf.x + hf.y * wf.y + hf.z * wf.z + hf.w * wf.w +
              hb.x * wb.x + hb.y * wb.y + hb.z * wb.z + hb.w * wb.w;
#pragma unroll
    for (int off = 32; off; off >>= 1) p += __shfl_xor(p, off, 64);
    if (lane == 0) feats[row * T_ + tag] = p + b_out[tag];
  }
}

// ---------------- K5: Viterbi fwd + backtrack, one wave per batch elem ----------------
__global__ __launch_bounds__(64) void k_viterbi(const float* __restrict__ feats,
                                                const float* __restrict__ trans,
                                                float* __restrict__ out) {
  __shared__ float fl[512 * T_];
  __shared__ unsigned char psi[511 * T_];
  const int b = blockIdx.x, tid = threadIdx.x;
  const float* fb = feats + (size_t)b * 512 * T_;
  for (int i = tid; i < 512 * T_; i += 64) fl[i] = fb[i];
  const int to = (tid < T_) ? tid : 0;
  float tr[T_];
#pragma unroll
  for (int f = 0; f < T_; ++f) tr[f] = trans[to * T_ + f];
  float delta = (tid == 9) ? 0.f : -10000.f;   // START=9
  __syncthreads();

  for (int s = 1; s < 512; ++s) {
    float m = -3.4e38f;
    int am = 0;
#pragma unroll
    for (int f = 0; f < T_; ++f) {
      float v = tr[f] + __shfl(delta, f, 64);
      if (v > m) { m = v; am = f; }          // strict >: first-max (jnp.argmax)
    }
    float nd = m + fl[s * T_ + to];
    if (tid < T_) psi[(s - 1) * T_ + tid] = (unsigned char)am;
    delta = nd;
  }
  // score + last tag (computed uniformly on all lanes)
  float m = -3.4e38f;
  int last = 0;
#pragma unroll
  for (int j = 0; j < T_; ++j) {
    float v = __shfl(delta, j, 64);
    if (v > m) { m = v; last = j; }
  }
  __syncthreads();   // psi visible
  if (tid == 0) {
    out[b] = m;
    float* path = out + 32 + (size_t)b * 512;
    path[511] = (float)last;
    int nxt = last;
    for (int k = 510; k >= 0; --k) {
      nxt = psi[k * T_ + nxt];
      path[k] = (float)nxt;
    }
  }
}

}  // namespace

extern "C" void kernel_launch(void* const* d_in, const int* in_sizes, int n_in,
                              void* d_out, int out_size, void* d_ws, size_t ws_size,
                              hipStream_t stream) {
  const int* sent     = (const int*)d_in[0];
  const float* embed  = (const float*)d_in[1];
  const float* w_ih_f = (const float*)d_in[2];
  const float* w_hh_f = (const float*)d_in[3];
  const float* b_ih_f = (const float*)d_in[4];
  const float* b_hh_f = (const float*)d_in[5];
  const float* w_ih_b = (const float*)d_in[6];
  const float* w_hh_b = (const float*)d_in[7];
  const float* b_ih_b = (const float*)d_in[8];
  const float* b_hh_b = (const float*)d_in[9];
  const float* h0     = (const float*)d_in[10];
  const float* c0     = (const float*)d_in[11];
  const float* w_out  = (const float*)d_in[12];
  const float* b_out  = (const float*)d_in[13];
  const float* trans  = (const float*)d_in[14];

  float* ws   = (float*)d_ws;
  float* x    = ws;                 // 16384*256       = 4,194,304
  float* G    = x + 4194304;        // 16384*2048      = 33,554,432
  float* hs_f = G + 33554432;       // 32*512*256      = 4,194,304
  float* hs_b = hs_f + 4194304;     // 4,194,304
  float* c_f  = hs_b + 4194304;     // 512*256         = 131,072
  float* c_b  = c_f + 131072;       // 131,072
  float* feats = c_b + 131072;      // 16384*11        = 180,224
  // total 46,579,712 floats = ~178 MiB of ws

  k_gather<<<4096, 256, 0, stream>>>(sent, embed, x);
  k_input_gemm<<<dim3(16, 128), 256, 0, stream>>>(x, w_ih_f, w_ih_b, b_ih_f,
                                                  b_hh_f, b_ih_b, b_hh_b, G);
  for (int t = 0; t < 32; ++t)
    k_lstm_step<<<dim3(8, 16, 2), 256, 0, stream>>>(G, w_hh_f, w_hh_b, h0, c0,
                                                    hs_f, hs_b, c_f, c_b, t);
  k_out_gemm<<<4096, 256, 0, stream>>>(hs_f, hs_b, w_out, b_out, feats);
  k_viterbi<<<32, 64, 0, stream>>>(feats, trans, (float*)d_out);
}